// Round 5
// baseline (544.738 us; speedup 1.0000x reference)
//
#include <hip/hip_runtime.h>

typedef unsigned short u16;
typedef unsigned int u32;
typedef __attribute__((ext_vector_type(8))) short bf16x8;
typedef __attribute__((ext_vector_type(4))) float f32x4;

// ---------- helpers ----------
__device__ __forceinline__ u16 f2b(float f) {           // fp32 -> bf16 RNE
  u32 u = __float_as_uint(f);
  u32 r = (u + 0x7fffu + ((u >> 16) & 1u)) >> 16;
  return (u16)r;
}
__device__ __forceinline__ float b2f(u16 b) {
  return __uint_as_float(((u32)b) << 16);
}

typedef const __attribute__((address_space(1))) unsigned int gas_u32;
typedef __attribute__((address_space(3))) unsigned int las_u32;
__device__ __forceinline__ void gload_lds16(const void* g, const void* l) {
  __builtin_amdgcn_global_load_lds((gas_u32*)(unsigned long long)g,
                                   (las_u32*)(unsigned long long)l, 16, 0, 0);
}

// ---------- cast fp32 -> bf16 ----------
__global__ __launch_bounds__(256) void cast_f32_bf16(const float* __restrict__ in,
                                                     u16* __restrict__ out, int n) {
  int i = (blockIdx.x * 256 + threadIdx.x) * 8;
  if (i >= n) return;
  float4 a = *(const float4*)(in + i);
  float4 b = *(const float4*)(in + i + 4);
  bf16x8 r;
  r[0] = (short)f2b(a.x); r[1] = (short)f2b(a.y);
  r[2] = (short)f2b(a.z); r[3] = (short)f2b(a.w);
  r[4] = (short)f2b(b.x); r[5] = (short)f2b(b.y);
  r[6] = (short)f2b(b.z); r[7] = (short)f2b(b.w);
  *(bf16x8*)(out + i) = r;
}

// ---------- transpose v: qkv[b*4096+t][2048+d] -> vT[b][d][t] ----------
__global__ __launch_bounds__(256) void transpose_v(const u16* __restrict__ qkv,
                                                   u16* __restrict__ vT) {
  __shared__ u16 sm[32][33];
  const int t0 = blockIdx.x * 32, d0 = blockIdx.y * 32, b = blockIdx.z;
  const int tx = threadIdx.x & 31, ty = threadIdx.x >> 5;
#pragma unroll
  for (int i = 0; i < 4; ++i) {
    int t = t0 + i * 8 + ty;
    sm[i * 8 + ty][tx] = qkv[(size_t)(b * 4096 + t) * 3072 + 2048 + d0 + tx];
  }
  __syncthreads();
#pragma unroll
  for (int i = 0; i < 4; ++i) {
    int d = d0 + i * 8 + ty;
    vT[((size_t)b * 1024 + d) * 4096 + t0 + tx] = sm[tx][i * 8 + ty];
  }
}

// ---------- row softmax, in-place bf16 [rows][4096] ----------
__global__ __launch_bounds__(256) void softmax_rows(u16* __restrict__ sc) {
  const size_t row = blockIdx.x;
  u16* p = sc + row * 4096;
  const int tid = threadIdx.x;
  const int wid = tid >> 6, lane = tid & 63;
  bf16x8 c0 = ((const bf16x8*)p)[tid];
  bf16x8 c1 = ((const bf16x8*)p)[tid + 256];
  float v[16];
#pragma unroll
  for (int j = 0; j < 8; ++j) { v[j] = b2f((u16)c0[j]); v[8 + j] = b2f((u16)c1[j]); }
  float mx = v[0];
#pragma unroll
  for (int j = 1; j < 16; ++j) mx = fmaxf(mx, v[j]);
#pragma unroll
  for (int off = 32; off; off >>= 1) mx = fmaxf(mx, __shfl_xor(mx, off));
  __shared__ float redm[4], reds[4];
  if (lane == 0) redm[wid] = mx;
  __syncthreads();
  mx = fmaxf(fmaxf(redm[0], redm[1]), fmaxf(redm[2], redm[3]));
  float s = 0.f;
#pragma unroll
  for (int j = 0; j < 16; ++j) { v[j] = __expf(v[j] - mx); s += v[j]; }
#pragma unroll
  for (int off = 32; off; off >>= 1) s += __shfl_xor(s, off);
  if (lane == 0) reds[wid] = s;
  __syncthreads();
  s = (reds[0] + reds[1]) + (reds[2] + reds[3]);
  float inv = 1.0f / s;
#pragma unroll
  for (int j = 0; j < 8; ++j) {
    c0[j] = (short)f2b(v[j] * inv);
    c1[j] = (short)f2b(v[8 + j] * inv);
  }
  ((bf16x8*)p)[tid] = c0;
  ((bf16x8*)p)[tid + 256] = c1;
}

// ======== 256x256 m201-style 8-phase BT GEMM (T1+T2+T3+T4+T5) ========
// C[M,N] = scale*(A[M,K].B[N,K]^T)(+bias[N]); 512 thr = 8 waves (2Mx4N),
// per-wave 128x64. K-tile BK=64; 2 K-tiles/iteration, 8 phases/iter.
// LDS 128KB = 2 slots x (A 32KB | B 32KB). st_16x32 swizzle (0-conflict,
// r2/r4-verified): lin = st*1024 + r16*64 + c32*2, phys = lin ^ bit5(bit9),
// same involution on stage-source decode and ds_read addr (rule #21).
// Phase = {ds_read quadrant | stage 1 half-tile (2 gloads) | barrier |
// lgkmcnt(0) | setprio(1) 16xMFMA setprio(0) | barrier}.
// Stage schedule (region freed one phase earlier, WAR-safe via end barrier):
//   P1,P2: A-s1(t+1)   P3,P4: B-s0(t+2)   P5,P6: A-s0(t+2)   P7,P8: B-s1(t+3)
// Counted vmcnt(4) ONLY at P4/P8 (FIFO: retires exactly through the tile
// needed next; 2 half-tiles stay in flight; never drains mid-loop).
template <int OUT_BF16, int HAS_BIAS>
__global__ __launch_bounds__(512, 2)
void gemm256(const u16* __restrict__ A, const u16* __restrict__ B,
             void* __restrict__ Cv, const float* __restrict__ bias,
             int K, int lda, int ldb, int ldc,
             long asb, long bsb, long csb, float scale, int gy) {
  __shared__ __align__(16) u16 lds[65536];  // 2 x (A 16384 u16 | B 16384 u16)
  const int tid = threadIdx.x;
  const int wid = tid >> 6, lane = tid & 63;
  const int wr = wid >> 2, wc = wid & 3;
  const int z = blockIdx.y;
  const int nwg = gridDim.x;          // always % 8 == 0 here
  const int orig = blockIdx.x;
  const int swzb = (orig & 7) * (nwg >> 3) + (orig >> 3);  // XCD chunk (T1)
  const int m0 = (swzb / gy) * 256;   // m-major within XCD chunk
  const int n0 = (swzb % gy) * 256;
  A += (size_t)z * asb;
  B += (size_t)z * bsb;

  // per-lane stage source for the 4 lines of a 32KB tile:
  // phys byte p -> linear (involution) -> (row, colE); BK=64 (128B rows)
  const u16* sA[4];
  const u16* sB[4];
#pragma unroll
  for (int j = 0; j < 4; ++j) {
    int p = j * 8192 + wid * 1024 + lane * 16;   // byte offset in 32KB tile
    int lin = p ^ (((p >> 9) & 1) << 5);
    int st = lin >> 10;
    int row = (st >> 1) * 16 + ((lin >> 6) & 15);
    int colE = (st & 1) * 32 + ((lin & 63) >> 1);
    sA[j] = A + (size_t)(m0 + row) * lda + colE;
    sB[j] = B + (size_t)(n0 + row) * ldb + colE;
  }
  const int NT = K >> 6;   // K-tiles of 64; NT even for all our shapes

  // stage one line L (8KB) of A/B into slot s at K-offset k0
#define SAL(s, L, k0) gload_lds16(sA[L] + (k0), lds + (s)*32768 + (L)*4096 + wid*512)
#define SBL(s, L, k0) gload_lds16(sB[L] + (k0), lds + (s)*32768 + 16384 + (L)*4096 + wid*512)

  const int fr = lane & 15;
  const int frq = fr * 64 + (((lane >> 4) * 16) ^ ((fr & 8) << 2));  // swz'd

  const char* ldsb = (const char*)lds;
  bf16x8 aF[8], bF[8];
  f32x4 acc[8][4] = {};

  // A-quadrant mh of slot sl -> aF[0..7]; B-quadrant nh -> bF[nh*4..nh*4+3]
#define RDA(sl, mh)                                                         \
  _Pragma("unroll") for (int m = 0; m < 4; ++m)                             \
  _Pragma("unroll") for (int kh = 0; kh < 2; ++kh)                          \
    aF[m*2+kh] = *(const bf16x8*)(ldsb + (sl)*65536 +                       \
                    ((wr*8 + (mh)*4 + m)*2 + kh)*1024 + frq);
#define RDB(sl, nh)                                                         \
  _Pragma("unroll") for (int n = 0; n < 2; ++n)                             \
  _Pragma("unroll") for (int kh = 0; kh < 2; ++kh)                          \
    bF[((nh)*2+n)*2+kh] = *(const bf16x8*)(ldsb + (sl)*65536 + 32768 +      \
                    ((wc*4 + (nh)*2 + n)*2 + kh)*1024 + frq);
#define MFMA16(mh, nh)                                                      \
  __builtin_amdgcn_s_barrier();                                             \
  asm volatile("s_waitcnt lgkmcnt(0)" ::: "memory");                        \
  __builtin_amdgcn_s_setprio(1);                                            \
  _Pragma("unroll") for (int m = 0; m < 4; ++m)                             \
  _Pragma("unroll") for (int n = 0; n < 2; ++n)                             \
  _Pragma("unroll") for (int kh = 0; kh < 2; ++kh)                          \
    acc[(mh)*4+m][(nh)*2+n] = __builtin_amdgcn_mfma_f32_16x16x32_bf16(      \
        aF[m*2+kh], bF[((nh)*2+n)*2+kh], acc[(mh)*4+m][(nh)*2+n], 0, 0, 0); \
  __builtin_amdgcn_s_setprio(0);                                            \
  __builtin_amdgcn_s_barrier();

  // prologue: tile0 (A+B) -> slot0; tile1 B -> slot1
  SAL(0, 0, 0); SAL(0, 1, 0); SAL(0, 2, 0); SAL(0, 3, 0);
  SBL(0, 0, 0); SBL(0, 1, 0); SBL(0, 2, 0); SBL(0, 3, 0);
  SBL(1, 0, 64); SBL(1, 1, 64); SBL(1, 2, 64); SBL(1, 3, 64);
  asm volatile("s_waitcnt vmcnt(4)" ::: "memory");  // tile0 landed
  __builtin_amdgcn_s_barrier();

  for (int t = 0; t < NT; t += 2) {
    const bool more = (t + 2 < NT);
    const int ka = (t + 1) << 6, kb = (t + 2) << 6, kc = (t + 3) << 6;
    // P1: slot0 (mh0,nh0); stage A-s1(t+1) h0
    RDA(0, 0); RDB(0, 0);
    SAL(1, 0, ka); SAL(1, 1, ka);
    MFMA16(0, 0);
    // P2: slot0 (mh0,nh1); stage A-s1(t+1) h1
    RDB(0, 1);
    SAL(1, 2, ka); SAL(1, 3, ka);
    MFMA16(0, 1);
    // P3: slot0 (mh1,nh0); stage B-s0(t+2) h0
    RDA(0, 1);
    if (more) { SBL(0, 0, kb); SBL(0, 1, kb); }
    MFMA16(1, 0);
    // P4: slot0 (mh1,nh1); stage B-s0(t+2) h1; vmcnt -> tile t+1 complete
    if (more) {
      SBL(0, 2, kb); SBL(0, 3, kb);
      asm volatile("s_waitcnt vmcnt(4)" ::: "memory");
    } else {
      asm volatile("s_waitcnt vmcnt(0)" ::: "memory");
    }
    MFMA16(1, 1);
    // P5: slot1 (mh0,nh0); stage A-s0(t+2) h0
    RDA(1, 0); RDB(1, 0);
    if (more) { SAL(0, 0, kb); SAL(0, 1, kb); }
    MFMA16(0, 0);
    // P6: slot1 (mh0,nh1); stage A-s0(t+2) h1
    RDB(1, 1);
    if (more) { SAL(0, 2, kb); SAL(0, 3, kb); }
    MFMA16(0, 1);
    // P7: slot1 (mh1,nh0); stage B-s1(t+3) h0
    RDA(1, 1);
    if (more) { SBL(1, 0, kc); SBL(1, 1, kc); }
    MFMA16(1, 0);
    // P8: slot1 (mh1,nh1); stage B-s1(t+3) h1; vmcnt -> tile t+2 complete
    if (more) {
      SBL(1, 2, kc); SBL(1, 3, kc);
      asm volatile("s_waitcnt vmcnt(4)" ::: "memory");
    }
    MFMA16(1, 1);
  }

  // epilogue: C/D layout col=lane&15, row=(lane>>4)*4+r  [m89-verified]
  const int cl = lane & 15, rg4 = (lane >> 4) * 4;
#pragma unroll
  for (int m = 0; m < 8; ++m) {
#pragma unroll
    for (int n = 0; n < 4; ++n) {
      const int gcol = n0 + wc * 64 + n * 16 + cl;
      const float bv = HAS_BIAS ? bias[gcol] : 0.0f;
#pragma unroll
      for (int r = 0; r < 4; ++r) {
        const int grow = m0 + wr * 128 + m * 16 + rg4 + r;
        const float v = acc[m][n][r] * scale + bv;
        if (OUT_BF16)
          ((u16*)Cv)[(size_t)z * csb + (size_t)grow * ldc + gcol] = f2b(v);
        else
          ((float*)Cv)[(size_t)z * csb + (size_t)grow * ldc + gcol] = v;
      }
    }
  }
#undef SAL
#undef SBL
#undef RDA
#undef RDB
#undef MFMA16
}

// ---------- launch ----------
extern "C" void kernel_launch(void* const* d_in, const int* in_sizes, int n_in,
                              void* d_out, int out_size, void* d_ws, size_t ws_size,
                              hipStream_t stream) {
  const float* x    = (const float*)d_in[0];
  const float* Wqkv = (const float*)d_in[1];
  const float* bqkv = (const float*)d_in[2];
  const float* Wout = (const float*)d_in[3];
  const float* bout = (const float*)d_in[4];
  float* out = (float*)d_out;

  char* ws = (char*)d_ws;
  const size_t NX = 16384ull * 1024;
  const size_t FIXED = 176160768ull;  // qkv 96MB + vT 32 + ctx 32 + w 8

  int c;
  if      (ws_size >= 134217728ull + FIXED) c = 4;
  else if (ws_size >=  67108864ull + FIXED) c = 2;
  else if (ws_size >=  33554432ull + FIXED) c = 1;
  else return;
  const size_t S0 = (size_t)c * 33554432ull;

  u16* xb    = (u16*)(ws);                       // dead before sc is written
  u16* sc    = (u16*)(ws);
  u16* qkvb  = (u16*)(ws + S0);
  u16* vT    = (u16*)(ws + S0 + 100663296ull);
  u16* ctxb  = (u16*)(ws + S0 + 134217728ull);
  u16* wqkvb = (u16*)(ws + S0 + 167772160ull);
  u16* woutb = (u16*)(ws + S0 + 174063616ull);

  cast_f32_bf16<<<dim3((int)(NX / 2048)), 256, 0, stream>>>(x, xb, (int)NX);
  cast_f32_bf16<<<dim3(1536), 256, 0, stream>>>(Wqkv, wqkvb, 3072 * 1024);
  cast_f32_bf16<<<dim3(512),  256, 0, stream>>>(Wout, woutb, 1024 * 1024);

  // qkv = x @ Wqkv^T + bqkv : M=16384 N=3072 K=1024, grid 768, gy=12
  gemm256<1, 1><<<dim3(768, 1), 512, 0, stream>>>(
      xb, wqkvb, qkvb, bqkv, 1024, 1024, 1024, 3072, 0, 0, 0, 1.0f, 12);

  transpose_v<<<dim3(128, 32, 4), 256, 0, stream>>>(qkvb, vT);

  for (int b0 = 0; b0 < 4; b0 += c) {
    const u16* qb = qkvb + (size_t)b0 * 4096 * 3072;
    // scores = (q @ k^T)/32 : M=N=4096 K=1024, grid 256 x c, gy=16
    gemm256<1, 0><<<dim3(256, c), 512, 0, stream>>>(
        qb, qb + 1024, sc, nullptr, 1024, 3072, 3072, 4096,
        4096L * 3072, 4096L * 3072, 4096L * 4096, 0.03125f, 16);
    softmax_rows<<<dim3(4096 * c), 256, 0, stream>>>(sc);
    // ctx = attn @ vT^T : M=4096 N=1024 K=4096, grid 64 x c, gy=4
    gemm256<1, 0><<<dim3(64, c), 512, 0, stream>>>(
        sc, vT + (size_t)b0 * 1024 * 4096, ctxb + (size_t)b0 * 4096 * 1024,
        nullptr, 4096, 4096, 4096, 1024,
        4096L * 4096, 1024L * 4096, 4096L * 1024, 1.0f, 4);
  }

  // out = ctx @ Wout^T + bout : M=16384 N=1024 K=1024, grid 256, gy=4
  gemm256<0, 1><<<dim3(256, 1), 512, 0, stream>>>(
      ctxb, woutb, out, bout, 1024, 1024, 1024, 1024, 0, 0, 0, 1.0f, 4);
}

// Round 6
// 538.009 us; speedup vs baseline: 1.0125x; 1.0125x over previous
//
#include <hip/hip_runtime.h>

typedef unsigned short u16;
typedef unsigned int u32;
typedef __attribute__((ext_vector_type(8))) short bf16x8;
typedef __attribute__((ext_vector_type(4))) float f32x4;

// ---------- helpers ----------
__device__ __forceinline__ u16 f2b(float f) {           // fp32 -> bf16 RNE
  u32 u = __float_as_uint(f);
  u32 r = (u + 0x7fffu + ((u >> 16) & 1u)) >> 16;
  return (u16)r;
}
__device__ __forceinline__ float b2f(u16 b) {
  return __uint_as_float(((u32)b) << 16);
}

typedef const __attribute__((address_space(1))) unsigned int gas_u32;
typedef __attribute__((address_space(3))) unsigned int las_u32;
__device__ __forceinline__ void gload_lds16(const void* g, const void* l) {
  __builtin_amdgcn_global_load_lds((gas_u32*)(unsigned long long)g,
                                   (las_u32*)(unsigned long long)l, 16, 0, 0);
}

// ---------- cast fp32 -> bf16 ----------
__global__ __launch_bounds__(256) void cast_f32_bf16(const float* __restrict__ in,
                                                     u16* __restrict__ out, int n) {
  int i = (blockIdx.x * 256 + threadIdx.x) * 8;
  if (i >= n) return;
  float4 a = *(const float4*)(in + i);
  float4 b = *(const float4*)(in + i + 4);
  bf16x8 r;
  r[0] = (short)f2b(a.x); r[1] = (short)f2b(a.y);
  r[2] = (short)f2b(a.z); r[3] = (short)f2b(a.w);
  r[4] = (short)f2b(b.x); r[5] = (short)f2b(b.y);
  r[6] = (short)f2b(b.z); r[7] = (short)f2b(b.w);
  *(bf16x8*)(out + i) = r;
}

// ---------- transpose v: qkv[b*4096+t][2048+d] -> vT[b][d][t] ----------
__global__ __launch_bounds__(256) void transpose_v(const u16* __restrict__ qkv,
                                                   u16* __restrict__ vT) {
  __shared__ u16 sm[32][33];
  const int t0 = blockIdx.x * 32, d0 = blockIdx.y * 32, b = blockIdx.z;
  const int tx = threadIdx.x & 31, ty = threadIdx.x >> 5;
#pragma unroll
  for (int i = 0; i < 4; ++i) {
    int t = t0 + i * 8 + ty;
    sm[i * 8 + ty][tx] = qkv[(size_t)(b * 4096 + t) * 3072 + 2048 + d0 + tx];
  }
  __syncthreads();
#pragma unroll
  for (int i = 0; i < 4; ++i) {
    int d = d0 + i * 8 + ty;
    vT[((size_t)b * 1024 + d) * 4096 + t0 + tx] = sm[tx][i * 8 + ty];
  }
}

// ---------- row softmax, in-place bf16 [rows][4096] ----------
__global__ __launch_bounds__(256) void softmax_rows(u16* __restrict__ sc) {
  const size_t row = blockIdx.x;
  u16* p = sc + row * 4096;
  const int tid = threadIdx.x;
  const int wid = tid >> 6, lane = tid & 63;
  bf16x8 c0 = ((const bf16x8*)p)[tid];
  bf16x8 c1 = ((const bf16x8*)p)[tid + 256];
  float v[16];
#pragma unroll
  for (int j = 0; j < 8; ++j) { v[j] = b2f((u16)c0[j]); v[8 + j] = b2f((u16)c1[j]); }
  float mx = v[0];
#pragma unroll
  for (int j = 1; j < 16; ++j) mx = fmaxf(mx, v[j]);
#pragma unroll
  for (int off = 32; off; off >>= 1) mx = fmaxf(mx, __shfl_xor(mx, off));
  __shared__ float redm[4], reds[4];
  if (lane == 0) redm[wid] = mx;
  __syncthreads();
  mx = fmaxf(fmaxf(redm[0], redm[1]), fmaxf(redm[2], redm[3]));
  float s = 0.f;
#pragma unroll
  for (int j = 0; j < 16; ++j) { v[j] = __expf(v[j] - mx); s += v[j]; }
#pragma unroll
  for (int off = 32; off; off >>= 1) s += __shfl_xor(s, off);
  if (lane == 0) reds[wid] = s;
  __syncthreads();
  s = (reds[0] + reds[1]) + (reds[2] + reds[3]);
  float inv = 1.0f / s;
#pragma unroll
  for (int j = 0; j < 8; ++j) {
    c0[j] = (short)f2b(v[j] * inv);
    c1[j] = (short)f2b(v[8 + j] * inv);
  }
  ((bf16x8*)p)[tid] = c0;
  ((bf16x8*)p)[tid + 256] = c1;
}

// ======== 256x256 8-phase BT GEMM, compiler-fenced + B-read-ahead ========
// C[M,N] = scale*(A[M,K].B[N,K]^T)(+bias[N]); 512 thr = 8 waves (2Mx4N),
// per-wave 128x64. 2 K-tiles (BK=64) per iteration, 8 phases.
// LDS 128KB = 2 slots x (A 32KB | B 32KB); st_16x32 swizzle (0-conflict),
// same involution on stage-source decode and ds_read addr.
// Fencing: ALL loop barriers are asm-with-memory (compiler cannot move DS ops
// across phases); sched_barrier(0) after each lgkmcnt(0) (rule #18).
// Reads: A-quad read in the pre-barrier gap (single aF buffer, VGPR cap);
// B-quad read INSIDE the phase after lgkmcnt(0) -> returns hide under the 16
// MFMAs, awaited at next phase's lgkmcnt(0). bA/bB ping-pong costs 0 extra
// VGPRs vs r5. Publish/WAR: every DS read is drained at the NEXT phase's
// open-lgkmcnt(0); all stage-writes land >=1 full phase after the target's
// last read; vmcnt 12->4 at P4/P8 only (never 0 mid-loop).
template <int OUT_BF16, int HAS_BIAS>
__global__ __launch_bounds__(512, 2)
void gemm256(const u16* __restrict__ A, const u16* __restrict__ B,
             void* __restrict__ Cv, const float* __restrict__ bias,
             int K, int lda, int ldb, int ldc,
             long asb, long bsb, long csb, float scale, int gy) {
  __shared__ __align__(16) u16 lds[65536];  // 2 x (A 16384 u16 | B 16384 u16)
  const int tid = threadIdx.x;
  const int wid = tid >> 6, lane = tid & 63;
  const int wr = wid >> 2, wc = wid & 3;
  const int z = blockIdx.y;
  const int nwg = gridDim.x;          // always % 8 == 0 here
  const int orig = blockIdx.x;
  const int swzb = (orig & 7) * (nwg >> 3) + (orig >> 3);  // XCD chunk (T1)
  const int m0 = (swzb / gy) * 256;   // m-major within XCD chunk
  const int n0 = (swzb % gy) * 256;
  A += (size_t)z * asb;
  B += (size_t)z * bsb;

  // per-lane stage source for the 4 lines of a 32KB tile:
  // phys byte p -> linear (involution) -> (row, colE); BK=64 (128B rows)
  const u16* sA[4];
  const u16* sB[4];
#pragma unroll
  for (int j = 0; j < 4; ++j) {
    int p = j * 8192 + wid * 1024 + lane * 16;   // byte offset in 32KB tile
    int lin = p ^ (((p >> 9) & 1) << 5);
    int st = lin >> 10;
    int row = (st >> 1) * 16 + ((lin >> 6) & 15);
    int colE = (st & 1) * 32 + ((lin & 63) >> 1);
    sA[j] = A + (size_t)(m0 + row) * lda + colE;
    sB[j] = B + (size_t)(n0 + row) * ldb + colE;
  }
  const int NT = K >> 6;   // K-tiles of 64; NT even, >=2 for all our shapes

#define SAL(s, L, k0) gload_lds16(sA[L] + (k0), lds + (s)*32768 + (L)*4096 + wid*512)
#define SBL(s, L, k0) gload_lds16(sB[L] + (k0), lds + (s)*32768 + 16384 + (L)*4096 + wid*512)
#define BAR() asm volatile("s_barrier" ::: "memory")
#define LGK0() { asm volatile("s_waitcnt lgkmcnt(0)" ::: "memory"); \
                 __builtin_amdgcn_sched_barrier(0); }
#define VMC4() asm volatile("s_waitcnt vmcnt(4)" ::: "memory")
#define VMC0() asm volatile("s_waitcnt vmcnt(0)" ::: "memory")

  const int fr = lane & 15;
  const int frq = fr * 64 + (((lane >> 4) * 16) ^ ((fr & 8) << 2));  // swz'd

  const char* ldsb = (const char*)lds;
  bf16x8 aF[8], bA[4], bB[4];
  f32x4 acc[8][4] = {};

#define RDA(sl, mh)                                                         \
  _Pragma("unroll") for (int m = 0; m < 4; ++m)                             \
  _Pragma("unroll") for (int kh = 0; kh < 2; ++kh)                          \
    aF[m*2+kh] = *(const bf16x8*)(ldsb + (sl)*65536 +                       \
                    ((wr*8 + (mh)*4 + m)*2 + kh)*1024 + frq);
#define RDB(sl, nh, D)                                                      \
  _Pragma("unroll") for (int n = 0; n < 2; ++n)                             \
  _Pragma("unroll") for (int kh = 0; kh < 2; ++kh)                          \
    D[n*2+kh] = *(const bf16x8*)(ldsb + (sl)*65536 + 32768 +                \
                    ((wc*4 + (nh)*2 + n)*2 + kh)*1024 + frq);
#define MFMAQ(mh, nh, D)                                                    \
  __builtin_amdgcn_s_setprio(1);                                            \
  _Pragma("unroll") for (int m = 0; m < 4; ++m)                             \
  _Pragma("unroll") for (int n = 0; n < 2; ++n)                             \
  _Pragma("unroll") for (int kh = 0; kh < 2; ++kh)                          \
    acc[(mh)*4+m][(nh)*2+n] = __builtin_amdgcn_mfma_f32_16x16x32_bf16(      \
        aF[m*2+kh], D[n*2+kh], acc[(mh)*4+m][(nh)*2+n], 0, 0, 0);           \
  __builtin_amdgcn_s_setprio(0);

  // prologue: tile0 (A+B) -> slot0; tile1 B -> slot1; then first B0 read
  SAL(0, 0, 0); SAL(0, 1, 0); SAL(0, 2, 0); SAL(0, 3, 0);
  SBL(0, 0, 0); SBL(0, 1, 0); SBL(0, 2, 0); SBL(0, 3, 0);
  SBL(1, 0, 64); SBL(1, 1, 64); SBL(1, 2, 64); SBL(1, 3, 64);
  VMC4();                      // tile0 retired; B-s1 still in flight
  BAR();                       // slot0 published
  RDB(0, 0, bA);               // B0-s0 for P1 (drained at P1's lgkmcnt(0))

  for (int t = 0; t < NT; t += 2) {
    const bool more = (t + 2 < NT);
    const int ka = (t + 1) << 6, kb = (t + 2) << 6, kc = (t + 3) << 6;
    // ---- gap/P1: A0-s0 reads; stage A-s1(t+1) h0
    RDA(0, 0);
    SAL(1, 0, ka); SAL(1, 1, ka);
    BAR(); LGK0();
    RDB(0, 1, bB);                    // read-ahead B1-s0 for P2
    MFMAQ(0, 0, bA);
    BAR();
    // ---- gap/P2: stage A-s1 h1
    SAL(1, 2, ka); SAL(1, 3, ka);
    BAR(); LGK0();
    MFMAQ(0, 1, bB);
    BAR();
    // ---- gap/P3: A1-s0 reads; stage B-s0(t+2) h0
    RDA(0, 1);
    if (more) { SBL(0, 0, kb); SBL(0, 1, kb); }
    BAR(); LGK0();
    MFMAQ(1, 0, bA);
    BAR();
    // ---- gap/P4: stage B-s0 h1; counted vmcnt -> slot1 (t+1) complete
    if (more) { SBL(0, 2, kb); SBL(0, 3, kb); VMC4(); }
    else      { VMC0(); }
    BAR(); LGK0();                    // slot1 published here
    RDB(1, 0, bA);                    // read-ahead B0-s1 for P5
    MFMAQ(1, 1, bB);
    BAR();
    // ---- gap/P5: A0-s1 reads; stage A-s0(t+2) h0
    RDA(1, 0);
    if (more) { SAL(0, 0, kb); SAL(0, 1, kb); }
    BAR(); LGK0();
    RDB(1, 1, bB);                    // read-ahead B1-s1 for P6
    MFMAQ(0, 0, bA);
    BAR();
    // ---- gap/P6: stage A-s0 h1
    if (more) { SAL(0, 2, kb); SAL(0, 3, kb); }
    BAR(); LGK0();
    MFMAQ(0, 1, bB);
    BAR();
    // ---- gap/P7: A1-s1 reads; stage B-s1(t+3) h0
    RDA(1, 1);
    if (more) { SBL(1, 0, kc); SBL(1, 1, kc); }
    BAR(); LGK0();
    MFMAQ(1, 0, bA);
    BAR();
    // ---- gap/P8: stage B-s1 h1; counted vmcnt -> slot0 (t+2) complete
    if (more) { SBL(1, 2, kc); SBL(1, 3, kc); VMC4(); }
    BAR(); LGK0();                    // slot0 (t+2) published here
    if (more) { RDB(0, 0, bA); }      // read-ahead B0-s0 for next P1
    MFMAQ(1, 1, bB);
    BAR();
  }

  // epilogue: C/D layout col=lane&15, row=(lane>>4)*4+r  [m89-verified]
  const int cl = lane & 15, rg4 = (lane >> 4) * 4;
#pragma unroll
  for (int m = 0; m < 8; ++m) {
#pragma unroll
    for (int n = 0; n < 4; ++n) {
      const int gcol = n0 + wc * 64 + n * 16 + cl;
      const float bv = HAS_BIAS ? bias[gcol] : 0.0f;
#pragma unroll
      for (int r = 0; r < 4; ++r) {
        const int grow = m0 + wr * 128 + m * 16 + rg4 + r;
        const float v = acc[m][n][r] * scale + bv;
        if (OUT_BF16)
          ((u16*)Cv)[(size_t)z * csb + (size_t)grow * ldc + gcol] = f2b(v);
        else
          ((float*)Cv)[(size_t)z * csb + (size_t)grow * ldc + gcol] = v;
      }
    }
  }
#undef SAL
#undef SBL
#undef BAR
#undef LGK0
#undef VMC4
#undef VMC0
#undef RDA
#undef RDB
#undef MFMAQ
}

// ---------- launch ----------
extern "C" void kernel_launch(void* const* d_in, const int* in_sizes, int n_in,
                              void* d_out, int out_size, void* d_ws, size_t ws_size,
                              hipStream_t stream) {
  const float* x    = (const float*)d_in[0];
  const float* Wqkv = (const float*)d_in[1];
  const float* bqkv = (const float*)d_in[2];
  const float* Wout = (const float*)d_in[3];
  const float* bout = (const float*)d_in[4];
  float* out = (float*)d_out;

  char* ws = (char*)d_ws;
  const size_t NX = 16384ull * 1024;
  const size_t FIXED = 176160768ull;  // qkv 96MB + vT 32 + ctx 32 + w 8

  int c;
  if      (ws_size >= 134217728ull + FIXED) c = 4;
  else if (ws_size >=  67108864ull + FIXED) c = 2;
  else if (ws_size >=  33554432ull + FIXED) c = 1;
  else return;
  const size_t S0 = (size_t)c * 33554432ull;

  u16* xb    = (u16*)(ws);                       // dead before sc is written
  u16* sc    = (u16*)(ws);
  u16* qkvb  = (u16*)(ws + S0);
  u16* vT    = (u16*)(ws + S0 + 100663296ull);
  u16* ctxb  = (u16*)(ws + S0 + 134217728ull);
  u16* wqkvb = (u16*)(ws + S0 + 167772160ull);
  u16* woutb = (u16*)(ws + S0 + 174063616ull);

  cast_f32_bf16<<<dim3((int)(NX / 2048)), 256, 0, stream>>>(x, xb, (int)NX);
  cast_f32_bf16<<<dim3(1536), 256, 0, stream>>>(Wqkv, wqkvb, 3072 * 1024);
  cast_f32_bf16<<<dim3(512),  256, 0, stream>>>(Wout, woutb, 1024 * 1024);

  // qkv = x @ Wqkv^T + bqkv : M=16384 N=3072 K=1024, grid 768, gy=12
  gemm256<1, 1><<<dim3(768, 1), 512, 0, stream>>>(
      xb, wqkvb, qkvb, bqkv, 1024, 1024, 1024, 3072, 0, 0, 0, 1.0f, 12);

  transpose_v<<<dim3(128, 32, 4), 256, 0, stream>>>(qkvb, vT);

  for (int b0 = 0; b0 < 4; b0 += c) {
    const u16* qb = qkvb + (size_t)b0 * 4096 * 3072;
    // scores = (q @ k^T)/32 : M=N=4096 K=1024, grid 256 x c, gy=16
    gemm256<1, 0><<<dim3(256, c), 512, 0, stream>>>(
        qb, qb + 1024, sc, nullptr, 1024, 3072, 3072, 4096,
        4096L * 3072, 4096L * 3072, 4096L * 4096, 0.03125f, 16);
    softmax_rows<<<dim3(4096 * c), 256, 0, stream>>>(sc);
    // ctx = attn @ vT^T : M=4096 N=1024 K=4096, grid 64 x c, gy=4
    gemm256<1, 0><<<dim3(64, c), 512, 0, stream>>>(
        sc, vT + (size_t)b0 * 1024 * 4096, ctxb + (size_t)b0 * 4096 * 1024,
        nullptr, 4096, 4096, 4096, 1024,
        4096L * 4096, 1024L * 4096, 4096L * 1024, 1.0f, 4);
  }

  // out = ctx @ Wout^T + bout : M=16384 N=1024 K=1024, grid 256, gy=4
  gemm256<0, 1><<<dim3(256, 1), 512, 0, stream>>>(
      ctxb, woutb, out, bout, 1024, 1024, 1024, 1024, 0, 0, 0, 1.0f, 4);
}